// Round 8
// baseline (80.145 us; speedup 1.0000x reference)
//
#include <hip/hip_runtime.h>

// x[256,1,58,58] -> conv5x5(64) -> maxpool2 -> conv5x5(128) -> linear(10)
//   -> out[256,23,23,10] f32
//
// R8: occupancy. Image split into 2 M-half blocks (512 blocks, 75.3 KB LDS
// each -> 2 blocks/CU, 4 waves/SIMD) so one block's MFMA overlaps the other's
// LDS/VMEM. conv2 = 32x32x16 MFMA, (4 mgrp x 2 ngrp), B per-ks from
// L2-resident w2d, <=3 M-tiles/wave (acc<=96 VGPR), launch_bounds(512,4).

typedef __attribute__((ext_vector_type(8))) short bf16x8;
typedef __attribute__((ext_vector_type(4))) float f32x4;
typedef __attribute__((ext_vector_type(16))) float f32x16;
typedef __attribute__((ext_vector_type(2))) unsigned int u32x2;
typedef __attribute__((ext_vector_type(4))) unsigned int u32x4;

#define MFMA16(a, b, c) __builtin_amdgcn_mfma_f32_16x16x32_bf16((a), (b), (c), 0, 0, 0)
#define MFMA32(a, b, c) __builtin_amdgcn_mfma_f32_32x32x16_bf16((a), (b), (c), 0, 0, 0)

static __device__ __forceinline__ unsigned short f2bf(float f) {
    unsigned u = __builtin_bit_cast(unsigned, f);
    u += 0x7FFFu + ((u >> 16) & 1u);   // RNE
    return (unsigned short)(u >> 16);
}

// ---- K0: w2[oc128][ic64][kk25] -> w2d fragment order for 32x32x16 B:
//   entry = kk*1024 + ks*256 + nt*64 + lane (16B each)
//   oc = nt*32 + (lane&31), ic = ks*16 + (lane>>5)*8 + j
__global__ __launch_bounds__(256) void prep_w2d(
    const float* __restrict__ w2, unsigned short* __restrict__ w2d)
{
    int t = blockIdx.x * 256 + threadIdx.x;        // 25600 entries
    if (t >= 25600) return;
    const int lane = t & 63, nt = (t >> 6) & 3, ks = (t >> 8) & 3, kk = t >> 10;
    const int oc = nt * 32 + (lane & 31);
    const int ic0 = ks * 16 + (lane >> 5) * 8;
    unsigned pk[4];
#pragma unroll
    for (int h = 0; h < 4; ++h) {
        unsigned short lo = f2bf(w2[oc * 1600 + (ic0 + 2 * h) * 25 + kk]);
        unsigned short hi = f2bf(w2[oc * 1600 + (ic0 + 2 * h + 1) * 25 + kk]);
        pk[h] = (unsigned)lo | ((unsigned)hi << 16);
    }
    u32x4 v; v.x = pk[0]; v.y = pk[1]; v.z = pk[2]; v.w = pk[3];
    *(u32x4*)(w2d + (size_t)t * 8) = v;
}

// LDS map (75280 B/block -> 2 blocks/CU):
//   xs   [0, 62424)        up to 459 pixel rows x 136B (64 bf16 + 8B pad)
//   xbf  [62424, 66832)    up to 38 input rows x 58 bf16
//   w1t  [66832, 70928)    [k32][oc64] bf16
//   lwT  [70928, 75280)    16 o rows x 272B
//   econ (overlays xs after K-loop): 4 mgrp x (32 rows x 272B) = 34816
#define XS_STR   136
#define XBF_OFF  62424
#define W1T_OFF  66832
#define LWT_OFF  70928
#define ECON_STR 272
#define ECON_TILE 8704
#define LDS_TOT  75280

__global__ __launch_bounds__(512, 4) void fused_net(
    const float* __restrict__ x, const float* __restrict__ w1,
    const unsigned short* __restrict__ w2d,
    const float* __restrict__ lw, const float* __restrict__ lb,
    float* __restrict__ out)
{
    extern __shared__ char lds[];
    unsigned short* xbf = (unsigned short*)(lds + XBF_OFF);
    unsigned short* w1t = (unsigned short*)(lds + W1T_OFF);
    const int h = blockIdx.x, b = blockIdx.y, tid = threadIdx.x;
    const int lane = tid & 63, w = tid >> 6;        // 8 waves
    const int l16 = lane & 15, kg = lane >> 4;      // 16x16 coords
    const int l32 = lane & 31, kg2 = lane >> 5;     // 32x32 coords
    const int mgrp = w >> 1, ngrp = w & 1;

    const int ph0   = h ? 12 : 0;     // first pooled row staged
    const int x0    = h ? 24 : 0;     // first input row staged
    const int nxrow = h ? 34 : 38;
    const int npx   = h ? 405 : 459;  // pooled pixels staged

    // ---- stage x rows -> xbf (bf16), w1 -> w1t, lw -> lwT ----
    const float* xb = x + b * 3364 + x0 * 58;
    const int nf2 = nxrow * 29;
    for (int i = tid; i < nf2; i += 512) {
        float2 v = ((const float2*)xb)[i];
        *(unsigned*)(xbf + i * 2) =
            (unsigned)f2bf(v.x) | ((unsigned)f2bf(v.y) << 16);
    }
    for (int i = tid; i < 2048; i += 512) {
        int k = i >> 6, oc = i & 63;
        w1t[i] = (k < 25) ? f2bf(w1[oc * 25 + k]) : (unsigned short)0;
    }
    for (int i = tid; i < 2048; i += 512) {
        int o = i >> 7, cc = i & 127;
        float v = (o < 10) ? lw[o * 128 + cc] : 0.f;
        *(unsigned short*)(lds + LWT_OFF + o * ECON_STR + cc * 2) = f2bf(v);
    }
    __syncthreads();

    // ================= conv1 + maxpool -> xs (local rows) =================
    {
        int koff[8];
        unsigned kmsk[8];
#pragma unroll
        for (int j = 0; j < 8; ++j) {
            int k = kg * 8 + j;
            int kh = k / 5, kw = k - 5 * kh;
            koff[j] = (k < 25) ? (kh * 58 + kw) : 0;
            kmsk[j] = (k < 25) ? 0xFFFFu : 0u;
        }
        bf16x8 bfrag[4];
#pragma unroll
        for (int ot = 0; ot < 4; ++ot)
#pragma unroll
            for (int j = 0; j < 8; ++j)
                bfrag[ot][j] = (short)w1t[(kg * 8 + j) * 64 + ot * 16 + l16];

        const f32x4 zero4 = {0.f, 0.f, 0.f, 0.f};
        const int nt4 = (npx + 3) >> 2;             // 115 / 102
        for (int t = w; t < nt4; t += 8) {
            int pl = t * 4 + (l16 >> 2);
            if (pl >= npx) pl = npx - 1;            // clamp (reads only)
            const int q = l16 & 3;
            const int pg = ph0 * 27 + pl;
            const int ph = pg / 27, pw = pg - 27 * ph;
            const int base = (2 * (ph - ph0) + (q >> 1)) * 58 + 2 * pw + (q & 1);
            bf16x8 afrag;
#pragma unroll
            for (int j = 0; j < 8; ++j)
                afrag[j] = (short)(xbf[base + koff[j]] & kmsk[j]);
            f32x4 acc1[4];
#pragma unroll
            for (int ot = 0; ot < 4; ++ot)
                acc1[ot] = MFMA16(afrag, bfrag[ot], zero4);
            const int pout = t * 4 + kg;
            if (pout < npx) {
#pragma unroll
                for (int ot = 0; ot < 4; ++ot) {
                    float m = fmaxf(fmaxf(acc1[ot][0], acc1[ot][1]),
                                    fmaxf(acc1[ot][2], acc1[ot][3]));
                    *(unsigned short*)(lds + pout * XS_STR + (ot * 16 + l16) * 2)
                        = f2bf(m);
                }
            }
        }
    }
    __syncthreads();   // xs complete

    // ============ conv2: 32x32x16, (4 mgrp x 2 ngrp), <=3 tiles/wave ========
    int ts[3], mcnt;
    if (h == 0) {                                   // 9 tiles: (3,2,2,2)
        if (mgrp == 0) { mcnt = 3; ts[0] = 0; ts[1] = 32; ts[2] = 64; }
        else { mcnt = 2; ts[0] = 96 + (mgrp - 1) * 64; ts[1] = ts[0] + 32;
               ts[2] = ts[0]; }
    } else {                                        // 8 tiles: (2,2,2,2)
        mcnt = 2; ts[0] = 288 + mgrp * 64;
        ts[1] = (mgrp == 3) ? 497 : ts[0] + 32;     // tail tile overlaps
        ts[2] = ts[0];
    }
    int abase[3];
#pragma unroll
    for (int i = 0; i < 3; ++i) {
        const int sp = ts[i] + l32;
        const int oh = sp / 23, ow = sp - oh * 23;
        abase[i] = ((oh - ph0) * 27 + ow) * XS_STR + kg2 * 16;
    }

    f32x16 acc[3][2];
#pragma unroll
    for (int i = 0; i < 3; ++i)
#pragma unroll
        for (int j = 0; j < 2; ++j)
#pragma unroll
            for (int r = 0; r < 16; ++r) acc[i][j][r] = 0.f;

    for (int kk = 0; kk < 25; ++kk) {
        const int kh = kk / 5, kw = kk - 5 * kh;
        const int pixoff = (kh * 27 + kw) * XS_STR;
        const unsigned short* wp = w2d + ((size_t)kk * 1024 + lane) * 8;
#pragma unroll
        for (int ks = 0; ks < 4; ++ks) {
            const bf16x8 B0 = *(const bf16x8*)(wp + (ks * 256 + (ngrp*2+0)*64) * 8);
            const bf16x8 B1 = *(const bf16x8*)(wp + (ks * 256 + (ngrp*2+1)*64) * 8);
#pragma unroll
            for (int i = 0; i < 3; ++i) {
                if (i < mcnt) {
                    const char* ap = lds + abase[i] + pixoff + ks * 32;
                    u32x2 lo = *(const u32x2*)(ap);
                    u32x2 hi = *(const u32x2*)(ap + 8);
                    u32x4 t4; t4.x = lo.x; t4.y = lo.y; t4.z = hi.x; t4.w = hi.y;
                    bf16x8 a = __builtin_bit_cast(bf16x8, t4);
                    acc[i][0] = MFMA32(a, B0, acc[i][0]);
                    acc[i][1] = MFMA32(a, B1, acc[i][1]);
                }
            }
        }
    }

    // ===== epilogue: per-mgrp econ (overlays xs) + linear MFMA, per tile =====
    char* myecon = lds + mgrp * ECON_TILE;
    const float lbv = (l16 < 10) ? lb[l16] : 0.f;

#define EPI(IT)                                                               \
    {                                                                         \
        __syncthreads();                                                      \
        if ((IT) < mcnt) {                                                    \
            _Pragma("unroll")                                                 \
            for (int j = 0; j < 2; ++j) {                                     \
                const int col = (ngrp * 2 + j) * 32 + l32;                    \
                _Pragma("unroll")                                             \
                for (int reg = 0; reg < 16; ++reg) {                          \
                    const int row = (reg & 3) + 8 * (reg >> 2) + 4 * kg2;     \
                    *(unsigned short*)(myecon + row * ECON_STR + col * 2)     \
                        = f2bf(acc[(IT)][j][reg]);                            \
                }                                                             \
            }                                                                 \
        }                                                                     \
        __syncthreads();                                                      \
        if ((IT) < mcnt) {                                                    \
            f32x4 al = {0.f, 0.f, 0.f, 0.f};                                  \
            const char* arow = myecon + (ngrp * 16 + l16) * ECON_STR + kg * 16;\
            const char* brow = lds + LWT_OFF + l16 * ECON_STR + kg * 16;      \
            _Pragma("unroll")                                                 \
            for (int ks = 0; ks < 4; ++ks) {                                  \
                bf16x8 av = *(const bf16x8*)(arow + ks * 64);                 \
                bf16x8 bv = *(const bf16x8*)(brow + ks * 64);                 \
                al = MFMA16(av, bv, al);                                      \
            }                                                                 \
            if (l16 < 10) {                                                   \
                _Pragma("unroll")                                             \
                for (int r = 0; r < 4; ++r) {                                 \
                    const int sp = ts[(IT)] + ngrp * 16 + kg * 4 + r;         \
                    out[((size_t)b * 529 + sp) * 10 + l16] = al[r] + lbv;     \
                }                                                             \
            }                                                                 \
        }                                                                     \
    }

    EPI(0);
    EPI(1);
    if (h == 0) { EPI(2); }   // block-uniform -> barriers legal
#undef EPI
}

extern "C" void kernel_launch(void* const* d_in, const int* in_sizes, int n_in,
                              void* d_out, int out_size, void* d_ws, size_t ws_size,
                              hipStream_t stream) {
    const float* x  = (const float*)d_in[0];
    const float* w1 = (const float*)d_in[1];
    const float* w2 = (const float*)d_in[2];
    const float* lw = (const float*)d_in[3];
    const float* lb = (const float*)d_in[4];
    float* out = (float*)d_out;

    unsigned short* w2d = (unsigned short*)d_ws;   // 400 KB fragment-ordered

    (void)hipFuncSetAttribute((const void*)fused_net,
                              hipFuncAttributeMaxDynamicSharedMemorySize,
                              LDS_TOT);

    prep_w2d<<<100, 256, 0, stream>>>(w2, w2d);
    fused_net<<<dim3(2, 256), 512, LDS_TOT, stream>>>(x, w1, w2d, lw, lb, out);
}

// Round 9
// 77.442 us; speedup vs baseline: 1.0349x; 1.0349x over previous
//
#include <hip/hip_runtime.h>

// x[256,1,58,58] -> conv5x5(64) -> maxpool2 -> conv5x5(128) -> linear(10)
//   -> out[256,23,23,10] f32
//
// R9 = R6 (best: 61us) + K-loop pipe-overlap:
//   * waves 4-7 iterate K-slices rotated by 12 (accumulation commutes) so the
//     two waves on each SIMD are always in different load/MFMA phases
//   * explicit hf-granular B double-buffer (BA/BB) - next phase's 8 B-frag
//     loads issue before current phase's 40 MFMAs
//   * s_setprio(1) around MFMA clusters
// conv2 = 16x16x32 MFMA; wave owns all 128 oc x 4-5 M-tiles; B from
// L2-resident fragment-ordered w2c; A from LDS xs (144B rows).

typedef __attribute__((ext_vector_type(8))) short bf16x8;
typedef __attribute__((ext_vector_type(4))) float f32x4;
typedef __attribute__((ext_vector_type(4))) unsigned int u32x4;

#define MFMA16(a, b, c) __builtin_amdgcn_mfma_f32_16x16x32_bf16((a), (b), (c), 0, 0, 0)

static __device__ __forceinline__ unsigned short f2bf(float f) {
    unsigned u = __builtin_bit_cast(unsigned, f);
    u += 0x7FFFu + ((u >> 16) & 1u);   // RNE
    return (unsigned short)(u >> 16);
}

// ---- K0: w2[oc128][ic64][kk25] f32 -> w2c fragment order:
//   w2c[kk*8192 + nt*1024 + hf*512 + lane*8 + j]
//     = bf16( w2[(nt*16+l16)*1600 + (hf*32 + kg*8 + j)*25 + kk] )
__global__ __launch_bounds__(256) void prep_w2c(
    const float* __restrict__ w2, unsigned short* __restrict__ w2c)
{
    int t = blockIdx.x * 256 + threadIdx.x;        // 25600 entries
    if (t >= 25600) return;
    const int lane = t & 63, hf = (t >> 6) & 1, nt = (t >> 7) & 7, kk = t >> 10;
    const int l16 = lane & 15, kg = lane >> 4;
    const int oc = nt * 16 + l16;
    const int icb = hf * 32 + kg * 8;
    unsigned pk[4];
#pragma unroll
    for (int h = 0; h < 4; ++h) {
        unsigned short lo = f2bf(w2[oc * 1600 + (icb + 2 * h) * 25 + kk]);
        unsigned short hi = f2bf(w2[oc * 1600 + (icb + 2 * h + 1) * 25 + kk]);
        pk[h] = (unsigned)lo | ((unsigned)hi << 16);
    }
    u32x4 v; v.x = pk[0]; v.y = pk[1]; v.z = pk[2]; v.w = pk[3];
    *(u32x4*)(w2c + (size_t)t * 8) = v;
}

// LDS map (152320 B):
//   conv phase: xs  [0, 104976)       729 pixel rows x 144B (64 bf16 + pad)
//               xbf [104976, 111704)  58x58 input as bf16
//               w1t [111704, 115800)  [k32][oc64] bf16
//   epilogue:   econ[0, 147968)       544 sp rows x 272B
//   always:     lwT [147968, 152320)  16 o rows x 272B
#define XBF_OFF  104976
#define W1T_OFF  111704
#define ECON_STR 272
#define LWT_OFF  147968
#define LDS_TOT  152320

__global__ __launch_bounds__(512, 2) void fused_net(
    const float* __restrict__ x, const float* __restrict__ w1,
    const unsigned short* __restrict__ w2c,
    const float* __restrict__ lw, const float* __restrict__ lb,
    float* __restrict__ out)
{
    extern __shared__ char lds[];
    unsigned short* xbf = (unsigned short*)(lds + XBF_OFF);
    unsigned short* w1t = (unsigned short*)(lds + W1T_OFF);
    const int b = blockIdx.x, tid = threadIdx.x;
    const int lane = tid & 63, w = tid >> 6;        // 8 waves
    const int l16 = lane & 15, kg = lane >> 4;

    // ---- stage x -> xbf (bf16), w1 -> w1t [k][oc], lw -> lwT ----
    const float4* xg = (const float4*)(x + b * 3364);
    for (int i = tid; i < 841; i += 512) {
        float4 v = xg[i];
        unsigned p0 = (unsigned)f2bf(v.x) | ((unsigned)f2bf(v.y) << 16);
        unsigned p1 = (unsigned)f2bf(v.z) | ((unsigned)f2bf(v.w) << 16);
        *(uint2*)(xbf + i * 4) = make_uint2(p0, p1);
    }
    for (int i = tid; i < 2048; i += 512) {
        int k = i >> 6, oc = i & 63;
        w1t[i] = (k < 25) ? f2bf(w1[oc * 25 + k]) : (unsigned short)0;
    }
    for (int i = tid; i < 2048; i += 512) {
        int o = i >> 7, cc = i & 127;
        float v = (o < 10) ? lw[o * 128 + cc] : 0.f;
        *(unsigned short*)(lds + LWT_OFF + o * 272 + cc * 2) = f2bf(v);
    }
    __syncthreads();

    // ================= conv1 + maxpool -> xs =================
    {
        int koff[8];
        unsigned kmsk[8];
#pragma unroll
        for (int j = 0; j < 8; ++j) {
            int k = kg * 8 + j;
            int kh = k / 5, kw = k - 5 * kh;
            koff[j] = (k < 25) ? (kh * 58 + kw) : 0;
            kmsk[j] = (k < 25) ? 0xFFFFu : 0u;
        }
        bf16x8 bfrag[4];
#pragma unroll
        for (int ot = 0; ot < 4; ++ot)
#pragma unroll
            for (int j = 0; j < 8; ++j)
                bfrag[ot][j] = (short)w1t[(kg * 8 + j) * 64 + ot * 16 + l16];

        const f32x4 zero4 = {0.f, 0.f, 0.f, 0.f};
        for (int t = w; t < 183; t += 8) {
            int p = t * 4 + (l16 >> 2);
            if (p > 728) p = 728;
            const int q = l16 & 3;
            const int ph = p / 27, pw = p - 27 * ph;
            const int base = (2 * ph + (q >> 1)) * 58 + 2 * pw + (q & 1);
            bf16x8 afrag;
#pragma unroll
            for (int j = 0; j < 8; ++j)
                afrag[j] = (short)(xbf[base + koff[j]] & kmsk[j]);
            f32x4 acc1[4];
#pragma unroll
            for (int ot = 0; ot < 4; ++ot)
                acc1[ot] = MFMA16(afrag, bfrag[ot], zero4);
            const int pout = t * 4 + kg;
            if (pout < 729) {
#pragma unroll
                for (int ot = 0; ot < 4; ++ot) {
                    float m = fmaxf(fmaxf(acc1[ot][0], acc1[ot][1]),
                                    fmaxf(acc1[ot][2], acc1[ot][3]));
                    *(unsigned short*)(lds + pout * 144 + (ot * 16 + l16) * 2)
                        = f2bf(m);
                }
            }
        }
    }
    __syncthreads();   // xs complete; conv1 scratch (xbf/w1t) now dead

    // ========== conv2: desynced, software-pipelined, barrier-free ==========
    // 34 tiles of 16 rows: tile t<33 starts at 16t; tile 33 starts at 513.
    // Wave w owns tiles {w, w+8, w+16, w+24 (,w+32 if <34)}.
    const int mtc = (w < 2) ? 5 : 4;
    int abase[5];
#pragma unroll
    for (int ti = 0; ti < 5; ++ti) {
        int tile = w + 8 * ti;
        if (tile > 33) tile = w;               // unused slot (w>=2), safe addr
        const int tstart = (tile == 33) ? 513 : tile * 16;
        const int sp = tstart + l16;
        const int oh = sp / 23, ow = sp - oh * 23;
        abase[ti] = (oh * 27 + ow) * 144 + kg * 16;
    }

    f32x4 acc[5][8];
#pragma unroll
    for (int ti = 0; ti < 5; ++ti)
#pragma unroll
        for (int nt = 0; nt < 8; ++nt)
            acc[ti][nt] = (f32x4){0.f, 0.f, 0.f, 0.f};

    auto loadBhf = [&](bf16x8* dst, int kkv, int hf) {
        const unsigned short* p =
            w2c + (size_t)kkv * 8192 + hf * 512 + lane * 8;
#pragma unroll
        for (int nt = 0; nt < 8; ++nt)
            dst[nt] = *(const bf16x8*)(p + nt * 1024);
    };
    auto computeHF = [&](int kkv, int hf, const bf16x8* B) {
        const int kh = kkv / 5, kw = kkv - 5 * kh;
        const int pixoff = (kh * 27 + kw) * 144 + hf * 64;
#pragma unroll
        for (int ti = 0; ti < 5; ++ti) {
            if (ti < mtc) {
                bf16x8 a = *(const bf16x8*)(lds + abase[ti] + pixoff);
#pragma unroll
                for (int nt = 0; nt < 8; ++nt)
                    acc[ti][nt] = MFMA16(a, B[nt], acc[ti][nt]);
            }
        }
    };

    // waves 0-3: slice order 0..24; waves 4-7: 12..24,0..11 (same SIMD pair
    // is always phase-shifted -> MFMA of one overlaps loads of the other)
    const int koffs = ((w >> 2) & 1) * 12;
    bf16x8 BA[8], BB[8];
    int kcur = koffs;
    loadBhf(BA, kcur, 0);
    for (int kk = 0; kk < 25; ++kk) {
        int knxt = kcur + 1;
        if (knxt >= 25) knxt -= 25;
        loadBhf(BB, kcur, 1);                       // prefetch hf=1
        __builtin_amdgcn_s_setprio(1);
        computeHF(kcur, 0, BA);
        __builtin_amdgcn_s_setprio(0);
        if (kk + 1 < 25) loadBhf(BA, knxt, 0);      // prefetch next slice hf=0
        __builtin_amdgcn_s_setprio(1);
        computeHF(kcur, 1, BB);
        __builtin_amdgcn_s_setprio(0);
        kcur = knxt;
    }

    // ================= epilogue: econ bf16 + linear MFMA =================
    __syncthreads();   // all waves done reading xs before econ overwrites it
#pragma unroll
    for (int ti = 0; ti < 5; ++ti) {
        if (ti < mtc) {
            int tile = w + 8 * ti;
            if (tile > 33) tile = w;
            const int rbase = ((tile == 33) ? 513 : tile * 16) + kg * 4;
#pragma unroll
            for (int nt = 0; nt < 8; ++nt) {
                const int col = nt * 16 + l16;
#pragma unroll
                for (int r = 0; r < 4; ++r)
                    *(unsigned short*)(lds + (rbase + r) * ECON_STR + col * 2)
                        = f2bf(acc[ti][nt][r]);
            }
        }
    }
    __syncthreads();

    const float lbv = (l16 < 10) ? lb[l16] : 0.f;
#pragma unroll
    for (int i = 0; i < 5; ++i) {
        const int t = w + 8 * i;
        if (t < 34) {
            f32x4 al = {0.f, 0.f, 0.f, 0.f};
            const char* arow = lds + (t * 16 + l16) * ECON_STR + kg * 16;
            const char* brow = lds + LWT_OFF + l16 * 272 + kg * 16;
#pragma unroll
            for (int ks = 0; ks < 4; ++ks) {
                bf16x8 av = *(const bf16x8*)(arow + ks * 64);
                bf16x8 bv = *(const bf16x8*)(brow + ks * 64);
                al = MFMA16(av, bv, al);
            }
            if (l16 < 10) {
#pragma unroll
                for (int r = 0; r < 4; ++r) {
                    int sp = t * 16 + kg * 4 + r;
                    if (sp < 529)
                        out[((size_t)b * 529 + sp) * 10 + l16] = al[r] + lbv;
                }
            }
        }
    }
}

extern "C" void kernel_launch(void* const* d_in, const int* in_sizes, int n_in,
                              void* d_out, int out_size, void* d_ws, size_t ws_size,
                              hipStream_t stream) {
    const float* x  = (const float*)d_in[0];
    const float* w1 = (const float*)d_in[1];
    const float* w2 = (const float*)d_in[2];
    const float* lw = (const float*)d_in[3];
    const float* lb = (const float*)d_in[4];
    float* out = (float*)d_out;

    unsigned short* w2c = (unsigned short*)d_ws;   // 400 KB fragment-ordered

    (void)hipFuncSetAttribute((const void*)fused_net,
                              hipFuncAttributeMaxDynamicSharedMemorySize,
                              LDS_TOT);

    prep_w2c<<<100, 256, 0, stream>>>(w2, w2c);
    fused_net<<<256, 512, LDS_TOT, stream>>>(x, w1, w2c, lw, lb, out);
}